// Round 9
// baseline (267.655 us; speedup 1.0000x reference)
//
#include <hip/hip_runtime.h>

// ---------------------------------------------------------------------------
// GraphNet: 2x GCNConv(128->128, relu) + global_mean_pool + Linear(128->16)
// N=50000, E=640000, G=64. fp32 accumulate, fp16 payloads + fp16 edge weights.
// R9: 4-byte CSR entries ((src<<16)|fp16(ew)) -> half the scatter/agg/deginv
// edge traffic; ushort rank array; nontemporal csr loads (keep L2 for the
// payload table); hipMemsetAsync for histogram zeroing. GEMM on MFMA
// (mfma_f32_16x16x32_f16, W packed once to B-frag order, no LDS). Chunked
// CSR (src>>13, 2MB fp16 windows) for L2-resident gathers. Fused pool+fc.
// ---------------------------------------------------------------------------

typedef _Float16 h4 __attribute__((ext_vector_type(4)));
typedef _Float16 h8 __attribute__((ext_vector_type(8)));
typedef float f32x4 __attribute__((ext_vector_type(4)));

// ONE atomic per edge on (dst, src-chunk) key: rank + histogram.
__global__ void rank_kernel(const int* __restrict__ row, const int* __restrict__ col,
                            int* __restrict__ cnt, unsigned short* __restrict__ rank,
                            int E, int C) {
    int e = blockIdx.x * blockDim.x + threadIdx.x;
    if (e >= E) return;
    int key = col[e] * C + (row[e] >> 13);
    rank[e] = (unsigned short)atomicAdd(&cnt[key], 1);
}

// --- multiblock exclusive scan of cnt[0..NC) -> rowptr[0..NC] ---
__global__ void block_sum_kernel(const int* __restrict__ cnt, int* __restrict__ bsum, int NC) {
    __shared__ int s[512];
    int t = threadIdx.x;
    int i = blockIdx.x * 512 + t;
    s[t] = (i < NC) ? cnt[i] : 0;
    __syncthreads();
    for (int off = 256; off > 0; off >>= 1) {
        if (t < off) s[t] += s[t + off];
        __syncthreads();
    }
    if (t == 0) bsum[blockIdx.x] = s[0];
}

__global__ void scan_bsum_kernel(const int* __restrict__ bsum, int* __restrict__ boff,
                                 int* __restrict__ rowptr, int NC, int nb) {
    __shared__ int s[1024];
    int t = threadIdx.x;
    int v = (t < nb) ? bsum[t] : 0;
    s[t] = v;
    __syncthreads();
    for (int off = 1; off < 1024; off <<= 1) {
        int u = (t >= off) ? s[t - off] : 0;
        __syncthreads();
        s[t] += u;
        __syncthreads();
    }
    if (t < nb) boff[t] = s[t] - v;
    if (t == nb - 1) rowptr[NC] = s[t];
}

__global__ void rowptr_kernel(const int* __restrict__ cnt, const int* __restrict__ boff,
                              int* __restrict__ rowptr, int NC) {
    __shared__ int s[512];
    int t = threadIdx.x;
    int i = blockIdx.x * 512 + t;
    int v = (i < NC) ? cnt[i] : 0;
    s[t] = v;
    __syncthreads();
    for (int off = 1; off < 512; off <<= 1) {
        int u = (t >= off) ? s[t - off] : 0;
        __syncthreads();
        s[t] += u;
        __syncthreads();
    }
    if (i < NC) rowptr[i] = boff[blockIdx.x] + s[t] - v;
}

// Atomic-free scatter: pos = rowptr[key] + rank. 4B entry (src<<16)|fp16(ew).
__global__ void scatter_kernel(const int* __restrict__ row, const int* __restrict__ col,
                               const float* __restrict__ ew,
                               const unsigned short* __restrict__ rank,
                               const int* __restrict__ rowptr,
                               unsigned int* __restrict__ csr, int E, int C) {
    int e = blockIdx.x * blockDim.x + threadIdx.x;
    if (e >= E) return;
    int r = row[e];
    int pos = rowptr[col[e] * C + (r >> 13)] + (int)rank[e];
    unsigned short hw = __builtin_bit_cast(unsigned short, (_Float16)ew[e]);
    csr[pos] = ((unsigned int)r << 16) | (unsigned int)hw;
}

// Fused: deg (half-wave-reduced CSR fp16 sum) -> dinv -> p = fp16(dinv * x).
__global__ __launch_bounds__(256) void deginv_convert_kernel(
        const float4* __restrict__ x4, const unsigned int* __restrict__ csr,
        const int* __restrict__ rowptr, float* __restrict__ dinv,
        h4* __restrict__ p16, int n, int C) {
    int node = blockIdx.x * 8 + (threadIdx.x >> 5);
    if (node >= n) return;
    int lane = threadIdx.x & 31;
    int beg = rowptr[node * C], end = rowptr[node * C + C];
    float sum = 0.0f;
    for (int k = beg + lane; k < end; k += 32) {
        unsigned int v = __builtin_nontemporal_load(csr + k);
        sum += (float)__builtin_bit_cast(_Float16, (unsigned short)(v & 0xffffu));
    }
#pragma unroll
    for (int m = 16; m >= 1; m >>= 1) sum += __shfl_xor(sum, m);
    float di = rsqrtf(1.0f + sum);   // self-loop weight 1
    if (lane == 0) dinv[node] = di;
    float4 v = x4[(size_t)node * 32 + lane];
    h4 h;
    h.x = (_Float16)(di * v.x); h.y = (_Float16)(di * v.y);
    h.z = (_Float16)(di * v.z); h.w = (_Float16)(di * v.w);
    p16[(size_t)node * 32 + lane] = h;
}

// One half-wave per node; lane owns 4 fp16 cols. fp32 acc. Chunk-ordered CSR.
// out = fp16( dinv[dst] * ( sum_e ew_e * p[src_e] + p[dst] ) )
__global__ __launch_bounds__(256) void agg_kernel(const h4* __restrict__ in16,
                                                  const int* __restrict__ rowptr,
                                                  const unsigned int* __restrict__ csr,
                                                  const float* __restrict__ dinv,
                                                  h4* __restrict__ out16, int n, int C) {
    int node = blockIdx.x * 8 + (threadIdx.x >> 5);
    if (node >= n) return;
    int lane = threadIdx.x & 31;
    float di = dinv[node];
    h4 v = in16[(size_t)node * 32 + lane];
    float ax = (float)v.x, ay = (float)v.y, az = (float)v.z, aw = (float)v.w;
    int beg = rowptr[node * C], end = rowptr[node * C + C];
    int idx = beg;
    for (; idx + 4 <= end; idx += 4) {
        unsigned int e0 = __builtin_nontemporal_load(csr + idx + 0);
        unsigned int e1 = __builtin_nontemporal_load(csr + idx + 1);
        unsigned int e2 = __builtin_nontemporal_load(csr + idx + 2);
        unsigned int e3 = __builtin_nontemporal_load(csr + idx + 3);
        h4 u0 = in16[(size_t)(e0 >> 16) * 32 + lane];
        h4 u1 = in16[(size_t)(e1 >> 16) * 32 + lane];
        h4 u2 = in16[(size_t)(e2 >> 16) * 32 + lane];
        h4 u3 = in16[(size_t)(e3 >> 16) * 32 + lane];
        float w0 = (float)__builtin_bit_cast(_Float16, (unsigned short)(e0 & 0xffffu));
        float w1 = (float)__builtin_bit_cast(_Float16, (unsigned short)(e1 & 0xffffu));
        float w2 = (float)__builtin_bit_cast(_Float16, (unsigned short)(e2 & 0xffffu));
        float w3 = (float)__builtin_bit_cast(_Float16, (unsigned short)(e3 & 0xffffu));
        ax += w0 * (float)u0.x; ay += w0 * (float)u0.y; az += w0 * (float)u0.z; aw += w0 * (float)u0.w;
        ax += w1 * (float)u1.x; ay += w1 * (float)u1.y; az += w1 * (float)u1.z; aw += w1 * (float)u1.w;
        ax += w2 * (float)u2.x; ay += w2 * (float)u2.y; az += w2 * (float)u2.z; aw += w2 * (float)u2.w;
        ax += w3 * (float)u3.x; ay += w3 * (float)u3.y; az += w3 * (float)u3.z; aw += w3 * (float)u3.w;
    }
    for (; idx < end; ++idx) {
        unsigned int e0 = __builtin_nontemporal_load(csr + idx);
        float ww = (float)__builtin_bit_cast(_Float16, (unsigned short)(e0 & 0xffffu));
        h4 u = in16[(size_t)(e0 >> 16) * 32 + lane];
        ax += ww * (float)u.x; ay += ww * (float)u.y;
        az += ww * (float)u.z; aw += ww * (float)u.w;
    }
    h4 r;
    r.x = (_Float16)(ax * di); r.y = (_Float16)(ay * di);
    r.z = (_Float16)(az * di); r.w = (_Float16)(aw * di);
    out16[(size_t)node * 32 + lane] = r;
}

// Pack W (128x128 fp32) into fp16 B-fragment order for mfma_f32_16x16x32_f16:
// Wp[((c*4+kb)*64 + lane)*8 + j] = W[kb*32 + (lane>>4)*8 + j][c*16 + (lane&15)]
__global__ __launch_bounds__(256) void packW_kernel(const float* __restrict__ W1,
                                                    const float* __restrict__ W2,
                                                    _Float16* __restrict__ Wp1,
                                                    _Float16* __restrict__ Wp2) {
    const float* W = blockIdx.x ? W2 : W1;
    _Float16* Wp = blockIdx.x ? Wp2 : Wp1;
    for (int i = threadIdx.x; i < 2048; i += 256) {
        int lane = i & 63, kc = i >> 6;       // kc = c*4+kb
        int c = kc >> 2, kb = kc & 3;
        int colq = lane & 15, quad = lane >> 4;
        h8 v;
#pragma unroll
        for (int j = 0; j < 8; ++j)
            v[j] = (_Float16)W[(kb * 32 + quad * 8 + j) * 128 + c * 16 + colq];
        ((h8*)Wp)[i] = v;
    }
}

// MFMA GEMM: out[i][:] = relu(A[i][:] @ W + b) (xdinv[i] if SCALE), fp16 out.
// One wave = 16 rows x 128 cols = 32 mfma. A-frags straight from global in
// native A-layout; B-frags from packed Wp (32KB, L2-hot). No LDS, no syncs.
template <int SCALE>
__global__ __launch_bounds__(256) void gemm_mfma(const _Float16* __restrict__ A,
                                                 const h8* __restrict__ Wp,
                                                 const float* __restrict__ bias,
                                                 const float* __restrict__ dinv,
                                                 _Float16* __restrict__ out16, int n) {
    int wid = threadIdx.x >> 6, lane = threadIdx.x & 63;
    int tb = blockIdx.x * 64 + wid * 16;        // tile row base
    if (tb >= n) return;
    int colq = lane & 15, quad = lane >> 4;

    int arow = tb + colq;                        // A-frag row (m = lane&15)
    if (arow >= n) arow = n - 1;
    const h8* Arow = (const h8*)(A + (size_t)arow * 128);
    h8 a[4];
#pragma unroll
    for (int kb = 0; kb < 4; ++kb) a[kb] = Arow[kb * 4 + quad];

    f32x4 acc[8];
#pragma unroll
    for (int c = 0; c < 8; ++c) acc[c] = (f32x4)(0.0f);

#pragma unroll
    for (int c = 0; c < 8; ++c) {
#pragma unroll
        for (int kb = 0; kb < 4; ++kb) {
            h8 b = Wp[(c * 4 + kb) * 64 + lane];
            acc[c] = __builtin_amdgcn_mfma_f32_16x16x32_f16(a[kb], b, acc[c], 0, 0, 0);
        }
    }

    // C/D layout: col = lane&15, row = quad*4 + reg.
#pragma unroll
    for (int c = 0; c < 8; ++c) {
        float bz = bias[c * 16 + colq];
#pragma unroll
        for (int r = 0; r < 4; ++r) {
            int row = tb + quad * 4 + r;
            if (row < n) {
                float v = fmaxf(acc[c][r] + bz, 0.0f);
                if (SCALE) v *= dinv[row];
                out16[(size_t)row * 128 + c * 16 + colq] = (_Float16)v;
            }
        }
    }
}

// Fused mean-pool (fp16 input, fp32 acc) + FC. One block per graph.
__global__ __launch_bounds__(256) void poolfc_kernel(const h4* __restrict__ h,
                                                     const int* __restrict__ batch,
                                                     const float* __restrict__ Wfc,
                                                     const float* __restrict__ bfc,
                                                     float* __restrict__ out, int n, int O) {
    int g = blockIdx.x;
    __shared__ int sb[2];
    __shared__ float4 red[256];
    __shared__ float pooled[128];
    int t = threadIdx.x;
    if (t < 2) {
        int target = g + t;
        int lo = 0, hi = n;
        while (lo < hi) { int m = (lo + hi) >> 1; if (batch[m] < target) lo = m + 1; else hi = m; }
        sb[t] = lo;
    }
    __syncthreads();
    int start = sb[0], end = sb[1], len = end - start;
    int gq = t & 31;
    int seg = t >> 5;
    float4 acc; acc.x = acc.y = acc.z = acc.w = 0.0f;
    for (int i = start + seg; i < end; i += 8) {
        h4 v = h[(size_t)i * 32 + gq];
        acc.x += (float)v.x; acc.y += (float)v.y;
        acc.z += (float)v.z; acc.w += (float)v.w;
    }
    red[seg * 32 + gq] = acc;
    __syncthreads();
    if (t < 128) {
        float4 a = red[t], b = red[t + 128];
        a.x += b.x; a.y += b.y; a.z += b.z; a.w += b.w;
        red[t] = a;
    }
    __syncthreads();
    if (t < 64) {
        float4 a = red[t], b = red[t + 64];
        a.x += b.x; a.y += b.y; a.z += b.z; a.w += b.w;
        red[t] = a;
    }
    __syncthreads();
    if (t < 32) {
        float4 a = red[t], b = red[t + 32];
        float inv = (len > 0) ? 1.0f / (float)len : 0.0f;
        pooled[t * 4 + 0] = (a.x + b.x) * inv;
        pooled[t * 4 + 1] = (a.y + b.y) * inv;
        pooled[t * 4 + 2] = (a.z + b.z) * inv;
        pooled[t * 4 + 3] = (a.w + b.w) * inv;
    }
    __syncthreads();
    if (t < O) {
        float a = bfc[t];
        for (int k = 0; k < 128; ++k) a += pooled[k] * Wfc[k * O + t];
        out[g * O + t] = a;
    }
}

extern "C" void kernel_launch(void* const* d_in, const int* in_sizes, int n_in,
                              void* d_out, int out_size, void* d_ws, size_t ws_size,
                              hipStream_t stream) {
    const float* x     = (const float*)d_in[0];
    const int*   ei    = (const int*)d_in[1];
    const float* ew    = (const float*)d_in[2];
    const int*   batch = (const int*)d_in[3];
    const float* W1    = (const float*)d_in[4];
    const float* b1    = (const float*)d_in[5];
    const float* W2    = (const float*)d_in[6];
    const float* b2    = (const float*)d_in[7];
    const float* Wfc   = (const float*)d_in[8];
    const float* bfc   = (const float*)d_in[9];
    float* out = (float*)d_out;

    const int n = in_sizes[0] / 128;        // 50000
    const int E = in_sizes[2];              // 640000
    const int O = in_sizes[9];              // 16
    const int G = out_size / O;             // 64
    const int* row = ei;
    const int* col = ei + E;
    const int C  = (n + 8191) >> 13;        // src chunks of 8192 rows (7)
    const int NC = n * C;                   // 350000 keys
    const int NB = (NC + 511) / 512;        // scan blocks (<=1024)

    // Workspace carve (256B-aligned)
    char* p = (char*)d_ws;
    auto alloc = [&](size_t bytes) {
        char* r = p;
        p += (bytes + 255) & ~(size_t)255;
        return r;
    };
    float* dinv    = (float*)alloc((size_t)n * 4);
    int*   cnt     = (int*)alloc((size_t)NC * 4);
    unsigned short* rank = (unsigned short*)alloc((size_t)E * 2);
    int*   rowptr  = (int*)alloc((size_t)(NC + 1) * 4);
    int*   bsum    = (int*)alloc((size_t)NB * 4);
    int*   boff    = (int*)alloc((size_t)NB * 4);
    unsigned int* csr = (unsigned int*)alloc((size_t)E * 4);
    h4*    p1      = (h4*)alloc((size_t)n * 128 * 2);   // payload1 = dinv*x
    h4*    agg16   = (h4*)alloc((size_t)n * 128 * 2);   // agg output (both layers)
    h4*    p2      = (h4*)alloc((size_t)n * 128 * 2);   // payload2 = dinv*h1
    h4*    h2      = (h4*)alloc((size_t)n * 128 * 2);   // final node features
    _Float16* Wp1  = (_Float16*)alloc(128 * 128 * 2);   // packed fp16 W1
    _Float16* Wp2  = (_Float16*)alloc(128 * 128 * 2);   // packed fp16 W2

    // --- CSR build (chunked by src>>13) + W pack ---
    hipMemsetAsync(cnt, 0, (size_t)NC * 4, stream);
    packW_kernel<<<2, 256, 0, stream>>>(W1, W2, Wp1, Wp2);
    rank_kernel<<<(E + 255) / 256, 256, 0, stream>>>(row, col, cnt, rank, E, C);
    block_sum_kernel<<<NB, 512, 0, stream>>>(cnt, bsum, NC);
    scan_bsum_kernel<<<1, 1024, 0, stream>>>(bsum, boff, rowptr, NC, NB);
    rowptr_kernel<<<NB, 512, 0, stream>>>(cnt, boff, rowptr, NC);
    scatter_kernel<<<(E + 255) / 256, 256, 0, stream>>>(row, col, ew, rank, rowptr, csr, E, C);
    deginv_convert_kernel<<<(n + 7) / 8, 256, 0, stream>>>((const float4*)x, csr, rowptr, dinv, p1, n, C);

    // --- layer 1 ---
    agg_kernel<<<(n + 7) / 8, 256, 0, stream>>>(p1, rowptr, csr, dinv, agg16, n, C);
    gemm_mfma<1><<<(n + 63) / 64, 256, 0, stream>>>((const _Float16*)agg16, (const h8*)Wp1,
                                                    b1, dinv, (_Float16*)p2, n);

    // --- layer 2 ---
    agg_kernel<<<(n + 7) / 8, 256, 0, stream>>>(p2, rowptr, csr, dinv, agg16, n, C);
    gemm_mfma<0><<<(n + 63) / 64, 256, 0, stream>>>((const _Float16*)agg16, (const h8*)Wp2,
                                                    b2, dinv, (_Float16*)h2, n);

    // --- fused mean-pool + fc ---
    poolfc_kernel<<<G, 256, 0, stream>>>(h2, batch, Wfc, bfc, out, n, O);
}

// Round 10
// 254.182 us; speedup vs baseline: 1.0530x; 1.0530x over previous
//
#include <hip/hip_runtime.h>

// ---------------------------------------------------------------------------
// GraphNet: 2x GCNConv(128->128, relu) + global_mean_pool + Linear(128->16)
// N=50000, E=640000, G=64. fp32 accumulate, fp16 payloads + fp16 edge weights.
// R10: un-chunked CSR (key = dst; chunking was structurally ineffective for
// L2 locality), col-only histogram fused with packW, 4B CSR entries
// ((src<<16)|fp16(ew)), ushort rank, parallel pool (512 blocks) + tiny FC.
// GEMM on MFMA (mfma_f32_16x16x32_f16, W packed to B-frag order, no LDS).
// ---------------------------------------------------------------------------

typedef _Float16 h4 __attribute__((ext_vector_type(4)));
typedef _Float16 h8 __attribute__((ext_vector_type(8)));
typedef float f32x4 __attribute__((ext_vector_type(4)));

// Fused: histogram (blocks < NBe) + packW (blocks NBe, NBe+1).
// packW: Wp[((c*4+kb)*64+lane)*8+j] = W[kb*32+(lane>>4)*8+j][c*16+(lane&15)]
__global__ void hist_pack_kernel(const int* __restrict__ col, int* __restrict__ cnt,
                                 unsigned short* __restrict__ rank, int E, int NBe,
                                 const float* __restrict__ W1, const float* __restrict__ W2,
                                 _Float16* __restrict__ Wp1, _Float16* __restrict__ Wp2) {
    if (blockIdx.x < (unsigned)NBe) {
        int e = blockIdx.x * 256 + threadIdx.x;
        if (e < E) rank[e] = (unsigned short)atomicAdd(&cnt[col[e]], 1);
        return;
    }
    int which = blockIdx.x - NBe;
    const float* W = which ? W2 : W1;
    _Float16* Wp = which ? Wp2 : Wp1;
    for (int i = threadIdx.x; i < 2048; i += 256) {
        int lane = i & 63, kc = i >> 6;       // kc = c*4+kb
        int c = kc >> 2, kb = kc & 3;
        int colq = lane & 15, quad = lane >> 4;
        h8 v;
#pragma unroll
        for (int j = 0; j < 8; ++j)
            v[j] = (_Float16)W[(kb * 32 + quad * 8 + j) * 128 + c * 16 + colq];
        ((h8*)Wp)[i] = v;
    }
}

// --- multiblock exclusive scan of cnt[0..n) -> rowptr[0..n] ---
__global__ void block_sum_kernel(const int* __restrict__ cnt, int* __restrict__ bsum, int NC) {
    __shared__ int s[512];
    int t = threadIdx.x;
    int i = blockIdx.x * 512 + t;
    s[t] = (i < NC) ? cnt[i] : 0;
    __syncthreads();
    for (int off = 256; off > 0; off >>= 1) {
        if (t < off) s[t] += s[t + off];
        __syncthreads();
    }
    if (t == 0) bsum[blockIdx.x] = s[0];
}

__global__ void scan_bsum_kernel(const int* __restrict__ bsum, int* __restrict__ boff,
                                 int* __restrict__ rowptr, int NC, int nb) {
    __shared__ int s[1024];
    int t = threadIdx.x;
    int v = (t < nb) ? bsum[t] : 0;
    s[t] = v;
    __syncthreads();
    for (int off = 1; off < 1024; off <<= 1) {
        int u = (t >= off) ? s[t - off] : 0;
        __syncthreads();
        s[t] += u;
        __syncthreads();
    }
    if (t < nb) boff[t] = s[t] - v;
    if (t == nb - 1) rowptr[NC] = s[t];
}

__global__ void rowptr_kernel(const int* __restrict__ cnt, const int* __restrict__ boff,
                              int* __restrict__ rowptr, int NC) {
    __shared__ int s[512];
    int t = threadIdx.x;
    int i = blockIdx.x * 512 + t;
    int v = (i < NC) ? cnt[i] : 0;
    s[t] = v;
    __syncthreads();
    for (int off = 1; off < 512; off <<= 1) {
        int u = (t >= off) ? s[t - off] : 0;
        __syncthreads();
        s[t] += u;
        __syncthreads();
    }
    if (i < NC) rowptr[i] = boff[blockIdx.x] + s[t] - v;
}

// Atomic-free scatter: pos = rowptr[dst] + rank. 4B entry (src<<16)|fp16(ew).
__global__ void scatter_kernel(const int* __restrict__ row, const int* __restrict__ col,
                               const float* __restrict__ ew,
                               const unsigned short* __restrict__ rank,
                               const int* __restrict__ rowptr,
                               unsigned int* __restrict__ csr, int E) {
    int e = blockIdx.x * blockDim.x + threadIdx.x;
    if (e >= E) return;
    int pos = rowptr[col[e]] + (int)rank[e];
    unsigned short hw = __builtin_bit_cast(unsigned short, (_Float16)ew[e]);
    csr[pos] = ((unsigned int)row[e] << 16) | (unsigned int)hw;
}

// Fused: deg (half-wave-reduced CSR fp16 sum) -> dinv -> p = fp16(dinv * x).
__global__ __launch_bounds__(256) void deginv_convert_kernel(
        const float4* __restrict__ x4, const unsigned int* __restrict__ csr,
        const int* __restrict__ rowptr, float* __restrict__ dinv,
        h4* __restrict__ p16, int n) {
    int node = blockIdx.x * 8 + (threadIdx.x >> 5);
    if (node >= n) return;
    int lane = threadIdx.x & 31;
    int beg = rowptr[node], end = rowptr[node + 1];
    float sum = 0.0f;
    for (int k = beg + lane; k < end; k += 32) {
        unsigned int v = __builtin_nontemporal_load(csr + k);
        sum += (float)__builtin_bit_cast(_Float16, (unsigned short)(v & 0xffffu));
    }
#pragma unroll
    for (int m = 16; m >= 1; m >>= 1) sum += __shfl_xor(sum, m);
    float di = rsqrtf(1.0f + sum);   // self-loop weight 1
    if (lane == 0) dinv[node] = di;
    float4 v = x4[(size_t)node * 32 + lane];
    h4 h;
    h.x = (_Float16)(di * v.x); h.y = (_Float16)(di * v.y);
    h.z = (_Float16)(di * v.z); h.w = (_Float16)(di * v.w);
    p16[(size_t)node * 32 + lane] = h;
}

// One half-wave per node; lane owns 4 fp16 cols. fp32 acc.
// out = fp16( dinv[dst] * ( sum_e ew_e * p[src_e] + p[dst] ) )
__global__ __launch_bounds__(256) void agg_kernel(const h4* __restrict__ in16,
                                                  const int* __restrict__ rowptr,
                                                  const unsigned int* __restrict__ csr,
                                                  const float* __restrict__ dinv,
                                                  h4* __restrict__ out16, int n) {
    int node = blockIdx.x * 8 + (threadIdx.x >> 5);
    if (node >= n) return;
    int lane = threadIdx.x & 31;
    float di = dinv[node];
    h4 v = in16[(size_t)node * 32 + lane];
    float ax = (float)v.x, ay = (float)v.y, az = (float)v.z, aw = (float)v.w;
    int beg = rowptr[node], end = rowptr[node + 1];
    int idx = beg;
    for (; idx + 4 <= end; idx += 4) {
        unsigned int e0 = __builtin_nontemporal_load(csr + idx + 0);
        unsigned int e1 = __builtin_nontemporal_load(csr + idx + 1);
        unsigned int e2 = __builtin_nontemporal_load(csr + idx + 2);
        unsigned int e3 = __builtin_nontemporal_load(csr + idx + 3);
        h4 u0 = in16[(size_t)(e0 >> 16) * 32 + lane];
        h4 u1 = in16[(size_t)(e1 >> 16) * 32 + lane];
        h4 u2 = in16[(size_t)(e2 >> 16) * 32 + lane];
        h4 u3 = in16[(size_t)(e3 >> 16) * 32 + lane];
        float w0 = (float)__builtin_bit_cast(_Float16, (unsigned short)(e0 & 0xffffu));
        float w1 = (float)__builtin_bit_cast(_Float16, (unsigned short)(e1 & 0xffffu));
        float w2 = (float)__builtin_bit_cast(_Float16, (unsigned short)(e2 & 0xffffu));
        float w3 = (float)__builtin_bit_cast(_Float16, (unsigned short)(e3 & 0xffffu));
        ax += w0 * (float)u0.x; ay += w0 * (float)u0.y; az += w0 * (float)u0.z; aw += w0 * (float)u0.w;
        ax += w1 * (float)u1.x; ay += w1 * (float)u1.y; az += w1 * (float)u1.z; aw += w1 * (float)u1.w;
        ax += w2 * (float)u2.x; ay += w2 * (float)u2.y; az += w2 * (float)u2.z; aw += w2 * (float)u2.w;
        ax += w3 * (float)u3.x; ay += w3 * (float)u3.y; az += w3 * (float)u3.z; aw += w3 * (float)u3.w;
    }
    for (; idx < end; ++idx) {
        unsigned int e0 = __builtin_nontemporal_load(csr + idx);
        float ww = (float)__builtin_bit_cast(_Float16, (unsigned short)(e0 & 0xffffu));
        h4 u = in16[(size_t)(e0 >> 16) * 32 + lane];
        ax += ww * (float)u.x; ay += ww * (float)u.y;
        az += ww * (float)u.z; aw += ww * (float)u.w;
    }
    h4 r;
    r.x = (_Float16)(ax * di); r.y = (_Float16)(ay * di);
    r.z = (_Float16)(az * di); r.w = (_Float16)(aw * di);
    out16[(size_t)node * 32 + lane] = r;
}

// MFMA GEMM: out[i][:] = relu(A[i][:] @ W + b) (xdinv[i] if SCALE), fp16 out.
// One wave = 16 rows x 128 cols = 32 mfma. A-frags straight from global in
// native A-layout; B-frags from packed Wp (32KB, L2-hot). No LDS, no syncs.
template <int SCALE>
__global__ __launch_bounds__(256) void gemm_mfma(const _Float16* __restrict__ A,
                                                 const h8* __restrict__ Wp,
                                                 const float* __restrict__ bias,
                                                 const float* __restrict__ dinv,
                                                 _Float16* __restrict__ out16, int n) {
    int wid = threadIdx.x >> 6, lane = threadIdx.x & 63;
    int tb = blockIdx.x * 64 + wid * 16;        // tile row base
    if (tb >= n) return;
    int colq = lane & 15, quad = lane >> 4;

    int arow = tb + colq;                        // A-frag row (m = lane&15)
    if (arow >= n) arow = n - 1;
    const h8* Arow = (const h8*)(A + (size_t)arow * 128);
    h8 a[4];
#pragma unroll
    for (int kb = 0; kb < 4; ++kb) a[kb] = Arow[kb * 4 + quad];

    f32x4 acc[8];
#pragma unroll
    for (int c = 0; c < 8; ++c) acc[c] = (f32x4)(0.0f);

#pragma unroll
    for (int c = 0; c < 8; ++c) {
#pragma unroll
        for (int kb = 0; kb < 4; ++kb) {
            h8 b = Wp[(c * 4 + kb) * 64 + lane];
            acc[c] = __builtin_amdgcn_mfma_f32_16x16x32_f16(a[kb], b, acc[c], 0, 0, 0);
        }
    }

    // C/D layout: col = lane&15, row = quad*4 + reg.
#pragma unroll
    for (int c = 0; c < 8; ++c) {
        float bz = bias[c * 16 + colq];
#pragma unroll
        for (int r = 0; r < 4; ++r) {
            int row = tb + quad * 4 + r;
            if (row < n) {
                float v = fmaxf(acc[c][r] + bz, 0.0f);
                if (SCALE) v *= dinv[row];
                out16[(size_t)row * 128 + c * 16 + colq] = (_Float16)v;
            }
        }
    }
}

// Parallel mean-pool partials: block (g, s) of G*8; 128 threads; fp16 input,
// fp32 acc; 128 float atomics per block into pooled[g][*] (pre-zeroed).
__global__ __launch_bounds__(128) void pool_partial(const h4* __restrict__ h,
                                                    const int* __restrict__ batch,
                                                    float* __restrict__ pooled,
                                                    int n, int splits) {
    int g = blockIdx.x / splits;
    int s = blockIdx.x % splits;
    __shared__ int sb[2];
    __shared__ float4 red[128];
    int t = threadIdx.x;
    if (t < 2) {
        int target = g + t;
        int lo = 0, hi = n;
        while (lo < hi) { int m = (lo + hi) >> 1; if (batch[m] < target) lo = m + 1; else hi = m; }
        sb[t] = lo;
    }
    __syncthreads();
    int start = sb[0], end = sb[1], len = end - start;
    int a = start + (int)((long long)len * s / splits);
    int b = start + (int)((long long)len * (s + 1) / splits);
    int gq = t & 31;     // column granule (4 cols)
    int seg = t >> 5;    // 0..3 row split
    float4 acc; acc.x = acc.y = acc.z = acc.w = 0.0f;
    for (int i = a + seg; i < b; i += 4) {
        h4 v = h[(size_t)i * 32 + gq];
        acc.x += (float)v.x; acc.y += (float)v.y;
        acc.z += (float)v.z; acc.w += (float)v.w;
    }
    red[seg * 32 + gq] = acc;
    __syncthreads();
    if (t < 64) {
        float4 u = red[t], w = red[t + 64];
        u.x += w.x; u.y += w.y; u.z += w.z; u.w += w.w;
        red[t] = u;
    }
    __syncthreads();
    if (t < 32) {
        float4 u = red[t], w = red[t + 32];
        atomicAdd(&pooled[g * 128 + t * 4 + 0], u.x + w.x);
        atomicAdd(&pooled[g * 128 + t * 4 + 1], u.y + w.y);
        atomicAdd(&pooled[g * 128 + t * 4 + 2], u.z + w.z);
        atomicAdd(&pooled[g * 128 + t * 4 + 3], u.w + w.w);
    }
}

// Final FC: out[g][o] = bfc[o] + (1/len_g) * sum_k pooled[g][k] * Wfc[k][o]
__global__ void fc_final(const float* __restrict__ pooled, const int* __restrict__ batch,
                         const float* __restrict__ Wfc, const float* __restrict__ bfc,
                         float* __restrict__ out, int n, int G, int O) {
    int gid = blockIdx.x * blockDim.x + threadIdx.x;
    if (gid >= G * O) return;
    int g = gid / O, o = gid % O;
    int lo = 0, hi = n;
    while (lo < hi) { int m = (lo + hi) >> 1; if (batch[m] < g) lo = m + 1; else hi = m; }
    int start = lo;
    lo = 0; hi = n;
    while (lo < hi) { int m = (lo + hi) >> 1; if (batch[m] < g + 1) lo = m + 1; else hi = m; }
    float inv = (lo > start) ? 1.0f / (float)(lo - start) : 0.0f;
    float a = bfc[o];
    for (int k = 0; k < 128; ++k) a += pooled[g * 128 + k] * inv * Wfc[k * O + o];
    out[gid] = a;
}

extern "C" void kernel_launch(void* const* d_in, const int* in_sizes, int n_in,
                              void* d_out, int out_size, void* d_ws, size_t ws_size,
                              hipStream_t stream) {
    const float* x     = (const float*)d_in[0];
    const int*   ei    = (const int*)d_in[1];
    const float* ew    = (const float*)d_in[2];
    const int*   batch = (const int*)d_in[3];
    const float* W1    = (const float*)d_in[4];
    const float* b1    = (const float*)d_in[5];
    const float* W2    = (const float*)d_in[6];
    const float* b2    = (const float*)d_in[7];
    const float* Wfc   = (const float*)d_in[8];
    const float* bfc   = (const float*)d_in[9];
    float* out = (float*)d_out;

    const int n = in_sizes[0] / 128;        // 50000
    const int E = in_sizes[2];              // 640000
    const int O = in_sizes[9];              // 16
    const int G = out_size / O;             // 64
    const int* row = ei;
    const int* col = ei + E;
    const int NB  = (n + 511) / 512;        // scan blocks (98)
    const int NBe = (E + 255) / 256;        // edge blocks (2500)

    // Workspace carve (256B-aligned). cnt+pooled adjacent -> one memset.
    char* p = (char*)d_ws;
    auto alloc = [&](size_t bytes) {
        char* r = p;
        p += (bytes + 255) & ~(size_t)255;
        return r;
    };
    int*   cnt     = (int*)alloc((size_t)n * 4);
    float* pooled  = (float*)alloc((size_t)G * 128 * 4);
    char*  zend    = p;                                  // end of zeroed region
    float* dinv    = (float*)alloc((size_t)n * 4);
    unsigned short* rank = (unsigned short*)alloc((size_t)E * 2);
    int*   rowptr  = (int*)alloc((size_t)(n + 1) * 4);
    int*   bsum    = (int*)alloc((size_t)NB * 4);
    int*   boff    = (int*)alloc((size_t)NB * 4);
    unsigned int* csr = (unsigned int*)alloc((size_t)E * 4);
    h4*    p1      = (h4*)alloc((size_t)n * 128 * 2);   // payload1 = dinv*x
    h4*    agg16   = (h4*)alloc((size_t)n * 128 * 2);   // agg output (both layers)
    h4*    p2      = (h4*)alloc((size_t)n * 128 * 2);   // payload2 = dinv*h1
    h4*    h2      = (h4*)alloc((size_t)n * 128 * 2);   // final node features
    _Float16* Wp1  = (_Float16*)alloc(128 * 128 * 2);   // packed fp16 W1
    _Float16* Wp2  = (_Float16*)alloc(128 * 128 * 2);   // packed fp16 W2

    // --- CSR build (dst-keyed) + W pack ---
    hipMemsetAsync(cnt, 0, (size_t)(zend - (char*)cnt), stream);
    hist_pack_kernel<<<NBe + 2, 256, 0, stream>>>(col, cnt, rank, E, NBe, W1, W2, Wp1, Wp2);
    block_sum_kernel<<<NB, 512, 0, stream>>>(cnt, bsum, n);
    scan_bsum_kernel<<<1, 1024, 0, stream>>>(bsum, boff, rowptr, n, NB);
    rowptr_kernel<<<NB, 512, 0, stream>>>(cnt, boff, rowptr, n);
    scatter_kernel<<<NBe, 256, 0, stream>>>(row, col, ew, rank, rowptr, csr, E);
    deginv_convert_kernel<<<(n + 7) / 8, 256, 0, stream>>>((const float4*)x, csr, rowptr, dinv, p1, n);

    // --- layer 1 ---
    agg_kernel<<<(n + 7) / 8, 256, 0, stream>>>(p1, rowptr, csr, dinv, agg16, n);
    gemm_mfma<1><<<(n + 63) / 64, 256, 0, stream>>>((const _Float16*)agg16, (const h8*)Wp1,
                                                    b1, dinv, (_Float16*)p2, n);

    // --- layer 2 ---
    agg_kernel<<<(n + 7) / 8, 256, 0, stream>>>(p2, rowptr, csr, dinv, agg16, n);
    gemm_mfma<0><<<(n + 63) / 64, 256, 0, stream>>>((const _Float16*)agg16, (const h8*)Wp2,
                                                    b2, dinv, (_Float16*)h2, n);

    // --- parallel mean-pool + final FC ---
    pool_partial<<<G * 8, 128, 0, stream>>>(h2, batch, pooled, n, 8);
    fc_final<<<(G * O + 255) / 256, 256, 0, stream>>>(pooled, batch, Wfc, bfc, out, n, G, O);
}